// Round 12
// baseline (148.746 us; speedup 1.0000x reference)
//
#include <hip/hip_runtime.h>
#include <math.h>

#define D 128
#define BKT_SHIFT 8
#define CHUNK 4096
#define CAP 5120    // per-bucket srcs capacity; E[bucket]=4096, +1024 = ~16 sigma
#define CAPC 56     // per-(chunk,bucket) tmp slot capacity; mean 16, P(>56) ~ 1e-15

typedef __attribute__((ext_vector_type(8))) short bf8;   // 8 bf16 = 4 VGPRs
typedef __attribute__((ext_vector_type(4))) float f4;    // MFMA accumulator

__device__ __forceinline__ float b2f(ushort u) {
    union { uint i; float f; } x; x.i = ((uint)u) << 16; return x.f;
}
__device__ __forceinline__ ushort f2b(float f) {
    union { float f; uint i; } x; x.f = f;
    uint i = x.i;
    i += 0x7fffu + ((i >> 16) & 1u);
    return (ushort)(i >> 16);
}

// ---------------------------------------------------------------------------
// Fused prep + scatter.  grid (ncnk, 3):
//  y<2 : LDS counting-sort of layer-y edge chunk by coarse bucket (dst>>8);
//        write runs into BUCKET-MAJOR private slots tmpf[layer][bkt][chunk][s]
//        (no atomics, no zero-init) + per-chunk counts.
//  y==2: x<4  -> transpose W into PRE-SWIZZLED bf16 W^T (byte ^= (row&7)<<4)
//        x>=4 -> convert embs f32 -> bf16 (grid-stride).
// ---------------------------------------------------------------------------
__global__ __launch_bounds__(256)
void prep_scatter(const int* __restrict__ ei0, const int* __restrict__ ei1, int E,
                  int ncnk, int* __restrict__ chunkcnt, uint* __restrict__ tmpf,
                  const float* __restrict__ embs, ushort* __restrict__ xb, long n4,
                  const float* __restrict__ Wl0, const float* __restrict__ Wr0,
                  const float* __restrict__ Wl1, const float* __restrict__ Wr1,
                  ushort* __restrict__ WTsw) {
    // smem: lhist@0 lstart@1024 lcur@2048 ws@3072 sw@3088
    __shared__ char smem[3088 + CHUNK * 4];
    const int t = threadIdx.x;

    if (blockIdx.y == 2) {
        if (blockIdx.x < 4) {
            const float* Wsrc = blockIdx.x == 0 ? Wl0 : blockIdx.x == 1 ? Wr0
                               : blockIdx.x == 2 ? Wl1 : Wr1;
            ushort* dstm = WTsw + (size_t)blockIdx.x * D * D;   // 32KB half
            ushort (*tile)[33] = (ushort(*)[33])smem;
            const int r  = t >> 3;
            const int c0 = (t & 7) * 4;
            for (int tt = 0; tt < 16; ++tt) {
                int ti = tt >> 2, tj = tt & 3;
                float4 v = *(const float4*)(Wsrc + (ti * 32 + r) * D + tj * 32 + c0);
                tile[r][c0 + 0] = f2b(v.x);
                tile[r][c0 + 1] = f2b(v.y);
                tile[r][c0 + 2] = f2b(v.z);
                tile[r][c0 + 3] = f2b(v.w);
                __syncthreads();
                int row = tj * 32 + r;
                int off = row * 256 + (ti * 32 + c0) * 2;
                int doff = off ^ ((row & 7) << 4);
                ushort4 o = { tile[c0 + 0][r], tile[c0 + 1][r],
                              tile[c0 + 2][r], tile[c0 + 3][r] };
                *(ushort4*)((char*)dstm + doff) = o;
                __syncthreads();
            }
            return;
        }
        long i = (long)(blockIdx.x - 4) * 256 + t;
        long stride = (long)(gridDim.x - 4) * 256;
        for (; i < n4; i += stride) {
            float4 v = ((const float4*)embs)[i];
            ushort4 o = { f2b(v.x), f2b(v.y), f2b(v.z), f2b(v.w) };
            ((ushort4*)xb)[i] = o;
        }
        return;
    }

    // ---- bucket scatter (layer = blockIdx.y) ----
    int* lhist  = (int*)smem;
    int* lstart = (int*)(smem + 1024);
    int* lcur   = (int*)(smem + 2048);
    int* ws     = (int*)(smem + 3072);
    uint* sw    = (uint*)(smem + 3088);
    const int layer = blockIdx.y;
    const int* ei = layer ? ei1 : ei0;
    uint* tbase = tmpf + (size_t)layer * 256 * ncnk * CAPC;
    const int e0 = blockIdx.x * CHUNK;
    const int cnt = min(CHUNK, E - e0);
    lhist[t] = 0;
    __syncthreads();
    for (int i = t; i < cnt; i += 256)
        atomicAdd(&lhist[ei[E + e0 + i] >> BKT_SHIFT], 1);
    __syncthreads();
    {   // exclusive scan lhist -> lstart, lcur
        int lane = t & 63, wid = t >> 6;
        int v = lhist[t];
        int incl = v;
        #pragma unroll
        for (int o = 1; o < 64; o <<= 1) { int u = __shfl_up(incl, o); if (lane >= o) incl += u; }
        if (lane == 63) ws[wid] = incl;
        __syncthreads();
        int wb = 0;
        #pragma unroll
        for (int w = 0; w < 3; ++w) if (w < wid) wb += ws[w];
        int excl = incl - v + wb;
        lstart[t] = excl;
        lcur[t] = excl;
    }
    __syncthreads();
    for (int i = t; i < cnt; i += 256) {
        int s = ei[e0 + i];
        int d = ei[E + e0 + i];
        int r = atomicAdd(&lcur[d >> BKT_SHIFT], 1);
        sw[r] = ((uint)d << 16) | (uint)s;
    }
    __syncthreads();
    chunkcnt[((size_t)layer * ncnk + blockIdx.x) * 256 + t] = min(lhist[t], CAPC);
    for (int i = t; i < cnt; i += 256) {
        uint w = sw[i];
        int b = w >> 24;
        int o = i - lstart[b];
        if (o < CAPC)
            tbase[((size_t)b * ncnk + blockIdx.x) * CAPC + o] = w;
    }
}

// ---------------------------------------------------------------------------
// one block per (bucket, layer): COALESCED read of the bucket's ncnk*CAPC
// slot array, validity via slot < ccnt[chunk]; LDS hist + scan -> per-node
// deg/offs (fixed base b*CAP); place srcs (ushort).
// ---------------------------------------------------------------------------
__global__ __launch_bounds__(256)
void exact_place(const uint* __restrict__ tmpf, const int* __restrict__ chunkcnt,
                 int ncnk,
                 int* __restrict__ o0, int* __restrict__ o1,
                 int* __restrict__ d0, int* __restrict__ d1,
                 ushort* __restrict__ s0, ushort* __restrict__ s1, int N) {
    const int layer = blockIdx.y;
    const int b = blockIdx.x;
    int* offs = layer ? o1 : o0;
    int* deg  = layer ? d1 : d0;
    ushort* srcs = layer ? s1 : s0;
    const uint* tp = tmpf + ((size_t)layer * 256 + b) * ncnk * CAPC;
    __shared__ int lh[256], lc[256], ccnt[256];
    __shared__ int ws[4];
    const int t = threadIdx.x;
    const int lane = t & 63, wid = t >> 6;
    const int node0 = b << BKT_SHIFT;
    const int bstart = b * CAP;
    const int total = ncnk * CAPC;

    lh[t] = 0;
    ccnt[t] = (t < ncnk) ? chunkcnt[((size_t)layer * ncnk + t) * 256 + b] : 0;
    __syncthreads();

    for (int i = t; i < total; i += 256) {
        int c = i / CAPC, s = i - c * CAPC;
        if (s < ccnt[c]) {
            uint w = tp[i];
            atomicAdd(&lh[(w >> 16) & 255], 1);
        }
    }
    __syncthreads();
    {   // exclusive scan lh -> per-node offsets
        int v = lh[t];
        int incl = v;
        #pragma unroll
        for (int o = 1; o < 64; o <<= 1) { int u = __shfl_up(incl, o); if (lane >= o) incl += u; }
        if (lane == 63) ws[wid] = incl;
        __syncthreads();
        int wb = 0;
        #pragma unroll
        for (int w = 0; w < 3; ++w) if (w < wid) wb += ws[w];
        int excl = incl - v + wb;
        int node = node0 + t;
        if (node < N) { offs[node] = bstart + excl; deg[node] = v; }
        lc[t] = bstart + excl;
    }
    __syncthreads();
    for (int i = t; i < total; i += 256) {
        int c = i / CAPC, s = i - c * CAPC;
        if (s < ccnt[c]) {
            uint w = tp[i];
            int p = atomicAdd(&lc[(w >> 16) & 255], 1);
            srcs[p] = (ushort)(w & 0xffff);
        }
    }
}

// ---------------------------------------------------------------------------
// gather-mean over bf16 rows: one wave per node, 16 lanes/edge, 16 edge-slots
// per iteration. srcs indices PRELOADED (one coalesced load, lane = slot) and
// broadcast via __shfl -> no srcs-load on the loop's critical path. Invalid
// slots resolve to row 0 (si default) -> L1-resident, weight 0.
// ---------------------------------------------------------------------------
__global__ __launch_bounds__(256)
void gather_mean_b(const ushort* __restrict__ xb, const ushort* __restrict__ srcs,
                   const int* __restrict__ offs, const int* __restrict__ deg,
                   ushort* __restrict__ meanb, int N) {
    int node = blockIdx.x * 4 + (threadIdx.x >> 6);
    if (node >= N) return;
    int lane = threadIdx.x & 63;
    int g = lane >> 4;                // slot group 0..3
    int c = (lane & 15) * 8;          // col base (8 bf16 = 16B per lane)
    int beg = offs[node], dc = deg[node];
    int si = 0;
    if (lane < dc) si = srcs[beg + lane];
    float a[8] = {0.f,0.f,0.f,0.f,0.f,0.f,0.f,0.f};
    const int cap = dc < 64 ? dc : 64;
    for (int kb = 0; kb < cap; kb += 16) {
        int i0 = kb + g, i1 = i0 + 4, i2 = i0 + 8, i3 = i0 + 12;
        int s0 = __shfl(si, i0);
        int s1 = __shfl(si, i1);
        int s2 = __shfl(si, i2);
        int s3 = __shfl(si, i3);
        float w0 = i0 < dc ? 1.f : 0.f;
        float w1 = i1 < dc ? 1.f : 0.f;
        float w2 = i2 < dc ? 1.f : 0.f;
        float w3 = i3 < dc ? 1.f : 0.f;
        bf8 v0 = *(const bf8*)(xb + (long)s0 * D + c);
        bf8 v1 = *(const bf8*)(xb + (long)s1 * D + c);
        bf8 v2 = *(const bf8*)(xb + (long)s2 * D + c);
        bf8 v3 = *(const bf8*)(xb + (long)s3 * D + c);
        #pragma unroll
        for (int q = 0; q < 8; ++q) {
            a[q] = fmaf(w0, b2f((ushort)v0[q]), a[q]);
            a[q] = fmaf(w1, b2f((ushort)v1[q]), a[q]);
            a[q] = fmaf(w2, b2f((ushort)v2[q]), a[q]);
            a[q] = fmaf(w3, b2f((ushort)v3[q]), a[q]);
        }
    }
    // rare tail: deg > 64
    for (int e = beg + 64 + g; e < beg + dc; e += 4) {
        int s = srcs[e];
        bf8 v = *(const bf8*)(xb + (long)s * D + c);
        #pragma unroll
        for (int q = 0; q < 8; ++q) a[q] += b2f((ushort)v[q]);
    }
    #pragma unroll
    for (int q = 0; q < 8; ++q) {
        a[q] += __shfl_xor(a[q], 16);
        a[q] += __shfl_xor(a[q], 32);
    }
    if (g == 0) {
        float inv = dc > 0 ? 1.0f / (float)dc : 0.0f;
        bf8 o;
        #pragma unroll
        for (int q = 0; q < 8; ++q) o[q] = (short)f2b(a[q] * inv);
        *(bf8*)(meanb + (long)node * D + c) = o;
    }
}

// ---------------------------------------------------------------------------
// MFMA dual GEMM: out[r] = act( mean[r] @ Wl + bias + x[r] @ Wr )
// W^T pre-swizzled in global; staged LINEARLY into LDS via global_load_lds.
// 4 waves/block, 32 rows/wave, 128 rows/block; interior fast path.
// Safe in-place (outb == xb): each wave reads/writes only its own rows.
// ---------------------------------------------------------------------------
template <int ACT>
__global__ __launch_bounds__(256, 2)
void gemm_mfma(const ushort* __restrict__ meanb, const ushort* __restrict__ xb,
               const ushort* __restrict__ WTsw,   // 64KB: [Wl 32KB][Wr 32KB]
               const float* __restrict__ bias, float* __restrict__ outf,
               ushort* __restrict__ outb, int N) {
    __shared__ ushort sW[2 * D * D];   // 64 KB, swizzled (copied linearly)
    const int t = threadIdx.x;
    const int lane = t & 63;
    const int wid  = t >> 6;           // 0..3

    {
        const char* src = (const char*)WTsw;
        char* dst = (char*)sW;
        #pragma unroll
        for (int i = 0; i < 16; ++i) {
            int off = i * 4096 + t * 16;
            __builtin_amdgcn_global_load_lds(
                (const __attribute__((address_space(1))) unsigned int*)(src + off),
                (__attribute__((address_space(3))) unsigned int*)(dst + off),
                16, 0, 0);
        }
    }

    const int r0   = blockIdx.x * 128 + wid * 32;
    const int arow = r0 + (lane & 15);
    const int kg   = lane >> 4;
    const bool full = (r0 + 32 <= N);
    bf8 z = {};
    bf8 am[8], ax[8];                  // [0..3]: rows arow, [4..7]: rows arow+16
    if (full) {
        #pragma unroll
        for (int m = 0; m < 4; ++m) {
            const long a0 = (long)arow * D + kg * 8 + m * 32;
            am[m]   = *(const bf8*)(meanb + a0);
            ax[m]   = *(const bf8*)(xb + a0);
            am[m+4] = *(const bf8*)(meanb + a0 + 16 * D);
            ax[m+4] = *(const bf8*)(xb + a0 + 16 * D);
        }
    } else {
        #pragma unroll
        for (int m = 0; m < 4; ++m) {
            const long a0 = (long)arow * D + kg * 8 + m * 32;
            if (arow < N)      { am[m]   = *(const bf8*)(meanb + a0);
                                 ax[m]   = *(const bf8*)(xb + a0); }
            else               { am[m]   = z; ax[m]   = z; }
            if (arow + 16 < N) { am[m+4] = *(const bf8*)(meanb + a0 + 16 * D);
                                 ax[m+4] = *(const bf8*)(xb + a0 + 16 * D); }
            else               { am[m+4] = z; ax[m+4] = z; }
        }
    }

    const int sxor = (lane & 7) << 4;
    int p[4];
    #pragma unroll
    for (int m = 0; m < 4; ++m)
        p[m] = (lane & 15) * 256 + ((kg * 16 + m * 64) ^ sxor);

    __syncthreads();   // drains global_load_lds too

    f4 acc0[8], acc1[8];
    #pragma unroll
    for (int n = 0; n < 8; ++n) { acc0[n] = (f4){0.f,0.f,0.f,0.f}; acc1[n] = (f4){0.f,0.f,0.f,0.f}; }

    #pragma unroll
    for (int m = 0; m < 4; ++m) {
        #pragma unroll
        for (int n = 0; n < 8; ++n) {
            bf8 bl = *(const bf8*)((const char*)sW + n * 4096 + p[m]);
            acc0[n] = __builtin_amdgcn_mfma_f32_16x16x32_bf16(am[m],     bl, acc0[n], 0, 0, 0);
            acc1[n] = __builtin_amdgcn_mfma_f32_16x16x32_bf16(am[m + 4], bl, acc1[n], 0, 0, 0);
        }
    }
    #pragma unroll
    for (int m = 0; m < 4; ++m) {
        #pragma unroll
        for (int n = 0; n < 8; ++n) {
            bf8 br = *(const bf8*)((const char*)sW + 32768 + n * 4096 + p[m]);
            acc0[n] = __builtin_amdgcn_mfma_f32_16x16x32_bf16(ax[m],     br, acc0[n], 0, 0, 0);
            acc1[n] = __builtin_amdgcn_mfma_f32_16x16x32_bf16(ax[m + 4], br, acc1[n], 0, 0, 0);
        }
    }

    // epilogue: D[row = kg*4 + r (+16)][col = n*16 + (lane&15)]
    const int col0  = lane & 15;
    const int orow0 = r0 + kg * 4;
    #pragma unroll
    for (int n = 0; n < 8; ++n) {
        const int col = n * 16 + col0;
        const float b = bias[col];
        #pragma unroll
        for (int r = 0; r < 4; ++r) {
            #pragma unroll
            for (int h = 0; h < 2; ++h) {
                const int row = orow0 + r + h * 16;
                if (!full && row >= N) continue;
                float v = (h ? acc1[n][r] : acc0[n][r]) + b;
                if (ACT) {
                    v = 0.5f * v * (1.0f + erff(v * 0.70710678118654752f));
                    outb[(long)row * D + col] = f2b(v);
                } else {
                    outf[(long)row * D + col] = v;
                }
            }
        }
    }
}

// ---------------------------------------------------------------------------
extern "C" void kernel_launch(void* const* d_in, const int* in_sizes, int n_in,
                              void* d_out, int out_size, void* d_ws, size_t ws_size,
                              hipStream_t stream) {
    const float* embs = (const float*)d_in[0];
    const int*   ei0  = (const int*)d_in[1];
    const int*   ei1  = (const int*)d_in[2];
    const float* Wl0  = (const float*)d_in[3];
    const float* bl0  = (const float*)d_in[4];
    const float* Wr0  = (const float*)d_in[5];
    const float* Wl1  = (const float*)d_in[6];
    const float* bl1  = (const float*)d_in[7];
    const float* Wr1  = (const float*)d_in[8];

    const int N = in_sizes[0] / D;
    const int E = in_sizes[1] / 2;
    float* out = (float*)d_out;

    const int nbkt = (N + 255) >> BKT_SHIFT;
    const int ncnk = (E + CHUNK - 1) / CHUNK;

    // ws layout
    char* w = (char*)d_ws;
    ushort* xb    = (ushort*)w;  w += (size_t)N * D * 2;      // embs bf16; layer-0 out in-place
    ushort* meanb = (ushort*)w;  w += (size_t)N * D * 2;
    ushort* WT    = (ushort*)w;  w += (size_t)4 * D * D * 2;  // pre-swizzled [Wl0|Wr0|Wl1|Wr1]
    int* chunkcnt = (int*)w;     w += (size_t)2 * ncnk * 256 * 4;
    int* offs0    = (int*)w;     w += (size_t)N * 4;
    int* offs1    = (int*)w;     w += (size_t)N * 4;
    int* deg0     = (int*)w;     w += (size_t)N * 4;
    int* deg1     = (int*)w;     w += (size_t)N * 4;
    uint* tmpf    = (uint*)w;    w += (size_t)2 * 256 * ncnk * CAPC * 4;
    ushort* srcs0 = (ushort*)w;  w += (size_t)256 * CAP * 2;
    ushort* srcs1 = (ushort*)w;

    const int ab = (N + 3) / 4;
    const int gb = (N + 127) / 128;

    prep_scatter<<<dim3(ncnk, 3), 256, 0, stream>>>(ei0, ei1, E, ncnk, chunkcnt, tmpf,
                                                    embs, xb, (long)N * D / 4,
                                                    Wl0, Wr0, Wl1, Wr1, WT);
    exact_place<<<dim3(nbkt, 2), 256, 0, stream>>>(tmpf, chunkcnt, ncnk,
                                                   offs0, offs1, deg0, deg1,
                                                   srcs0, srcs1, N);

    // ---- layer 0 ----
    gather_mean_b<<<ab, 256, 0, stream>>>(xb, srcs0, offs0, deg0, meanb, N);
    gemm_mfma<1><<<gb, 256, 0, stream>>>(meanb, xb, WT, bl0, nullptr, xb, N);

    // ---- layer 1 ----
    gather_mean_b<<<ab, 256, 0, stream>>>(xb, srcs1, offs1, deg1, meanb, N);
    gemm_mfma<0><<<gb, 256, 0, stream>>>(meanb, xb, WT + 2 * D * D, bl1, out, nullptr, N);
}

// Round 13
// 138.678 us; speedup vs baseline: 1.0726x; 1.0726x over previous
//
#include <hip/hip_runtime.h>
#include <math.h>

#define D 128
#define BKT_SHIFT 8
#define CHUNK 4096
#define CAP 5120   // fixed per-bucket tmp capacity; E[bucket]=4096, sigma=64

typedef __attribute__((ext_vector_type(8))) short bf8;   // 8 bf16 = 4 VGPRs
typedef __attribute__((ext_vector_type(4))) float f4;    // MFMA accumulator

__device__ __forceinline__ float b2f(ushort u) {
    union { uint i; float f; } x; x.i = ((uint)u) << 16; return x.f;
}
// f32 -> bf16 round-to-nearest-even (finite inputs)
__device__ __forceinline__ ushort f2b(float f) {
    union { float f; uint i; } x; x.f = f;
    uint i = x.i;
    i += 0x7fffu + ((i >> 16) & 1u);
    return (ushort)(i >> 16);
}

// ---------------------------------------------------------------------------
// micro-kernel: zero the bucket cursors (must precede prep_scatter)
// ---------------------------------------------------------------------------
__global__ void zero_gbc(int* __restrict__ gbc) { gbc[threadIdx.x] = 0; }

// ---------------------------------------------------------------------------
// Fused prep + scatter.  grid (ncnk, 3):
//  y<2 : LDS counting-sort of layer-y edge chunk by coarse bucket (dst>>8);
//        reserve space via one atomic per (block,bucket); flush packed words
//        (dst16<<16 | src16) in coalesced runs into fixed-cap bucket regions.
//  y==2: x<4  -> transpose W (f32 row-major) into PRE-SWIZZLED bf16 W^T
//               (layout matches gemm LDS: byte off ^= (row&7)<<4), via
//               32x32 LDS tiles (2.1KB).
//        x>=4 -> convert embs f32 -> bf16 (grid-stride).
// ---------------------------------------------------------------------------
__global__ __launch_bounds__(256)
void prep_scatter(const int* __restrict__ ei0, const int* __restrict__ ei1, int E,
                  int* __restrict__ gbc, uint* __restrict__ tmpf,
                  const float* __restrict__ embs, ushort* __restrict__ xb, long n4,
                  const float* __restrict__ Wl0, const float* __restrict__ Wr0,
                  const float* __restrict__ Wl1, const float* __restrict__ Wr1,
                  ushort* __restrict__ WTsw) {
    // smem layout: lhist@0 lstart@1024 lcur@2048 gbase@3072 ws@4096 sw@4112
    __shared__ char smem[4112 + CHUNK * 4];
    const int t = threadIdx.x;

    if (blockIdx.y == 2) {
        if (blockIdx.x < 4) {
            // ---- W transpose + swizzle: one matrix per block ----
            const float* Wsrc = blockIdx.x == 0 ? Wl0 : blockIdx.x == 1 ? Wr0
                               : blockIdx.x == 2 ? Wl1 : Wr1;
            ushort* dstm = WTsw + (size_t)blockIdx.x * D * D;   // 32KB half
            ushort (*tile)[33] = (ushort(*)[33])smem;
            const int r  = t >> 3;
            const int c0 = (t & 7) * 4;
            for (int tt = 0; tt < 16; ++tt) {
                int ti = tt >> 2, tj = tt & 3;
                float4 v = *(const float4*)(Wsrc + (ti * 32 + r) * D + tj * 32 + c0);
                tile[r][c0 + 0] = f2b(v.x);
                tile[r][c0 + 1] = f2b(v.y);
                tile[r][c0 + 2] = f2b(v.z);
                tile[r][c0 + 3] = f2b(v.w);
                __syncthreads();
                // out element (row = W col, k = W row): 4 k's per thread
                int row = tj * 32 + r;
                int off = row * 256 + (ti * 32 + c0) * 2;      // linear byte in 32KB
                int doff = off ^ ((row & 7) << 4);             // swizzle
                ushort4 o = { tile[c0 + 0][r], tile[c0 + 1][r],
                              tile[c0 + 2][r], tile[c0 + 3][r] };
                *(ushort4*)((char*)dstm + doff) = o;
                __syncthreads();
            }
            return;
        }
        // ---- embs f32 -> bf16 ----
        long i = (long)(blockIdx.x - 4) * 256 + t;
        long stride = (long)(gridDim.x - 4) * 256;
        for (; i < n4; i += stride) {
            float4 v = ((const float4*)embs)[i];
            ushort4 o = { f2b(v.x), f2b(v.y), f2b(v.z), f2b(v.w) };
            ((ushort4*)xb)[i] = o;
        }
        return;
    }

    // ---- bucket scatter (layer = blockIdx.y) ----
    int* lhist  = (int*)smem;
    int* lstart = (int*)(smem + 1024);
    int* lcur   = (int*)(smem + 2048);
    int* gbase  = (int*)(smem + 3072);
    int* ws     = (int*)(smem + 4096);
    uint* sw    = (uint*)(smem + 4112);
    const int layer = blockIdx.y;
    const int* ei = layer ? ei1 : ei0;
    int* cnts = gbc + layer * 256;
    uint* tp = tmpf + (size_t)layer * 256 * CAP;
    const int e0 = blockIdx.x * CHUNK;
    const int cnt = min(CHUNK, E - e0);
    lhist[t] = 0;
    __syncthreads();
    for (int i = t; i < cnt; i += 256)
        atomicAdd(&lhist[ei[E + e0 + i] >> BKT_SHIFT], 1);
    __syncthreads();
    {   // exclusive scan lhist -> lstart, lcur
        int lane = t & 63, wid = t >> 6;
        int v = lhist[t];
        int incl = v;
        #pragma unroll
        for (int o = 1; o < 64; o <<= 1) { int u = __shfl_up(incl, o); if (lane >= o) incl += u; }
        if (lane == 63) ws[wid] = incl;
        __syncthreads();
        int wb = 0;
        #pragma unroll
        for (int w = 0; w < 3; ++w) if (w < wid) wb += ws[w];
        int excl = incl - v + wb;
        lstart[t] = excl;
        lcur[t] = excl;
    }
    __syncthreads();
    for (int i = t; i < cnt; i += 256) {
        int s = ei[e0 + i];
        int d = ei[E + e0 + i];
        int r = atomicAdd(&lcur[d >> BKT_SHIFT], 1);
        sw[r] = ((uint)d << 16) | (uint)s;
    }
    __syncthreads();
    gbase[t] = lhist[t] > 0 ? atomicAdd(&cnts[t], lhist[t]) : 0;
    __syncthreads();
    for (int i = t; i < cnt; i += 256) {
        uint w = sw[i];
        int b = w >> 24;                       // dst>>8
        tp[(size_t)b * CAP + gbase[b] + (i - lstart[b])] = w;
    }
}

// ---------------------------------------------------------------------------
// one block per bucket; re-computes the bucket-base scan from gbc in LDS,
// then per-node deg/offs (LDS hist + scan, coalesced writes), then
// exact-place srcs (ushort) into the bucket's contiguous region.
// ---------------------------------------------------------------------------
__global__ __launch_bounds__(256)
void exact_place(const uint* __restrict__ tmpf, const int* __restrict__ gbc,
                 int* __restrict__ o0, int* __restrict__ o1,
                 int* __restrict__ d0, int* __restrict__ d1,
                 ushort* __restrict__ s0, ushort* __restrict__ s1, int N) {
    const int layer = blockIdx.y;
    const uint* tp = tmpf + ((size_t)layer * 256 + blockIdx.x) * CAP;
    int* offs = layer ? o1 : o0;
    int* deg  = layer ? d1 : d0;
    ushort* srcs = layer ? s1 : s0;
    __shared__ int lh[256], lc[256], sbase[256];
    __shared__ int ws[4];
    const int t = threadIdx.x;
    const int lane = t & 63, wid = t >> 6;
    const int node0 = blockIdx.x << BKT_SHIFT;

    // ---- scan bucket counts -> this bucket's base ----
    {
        int v = gbc[layer * 256 + t];
        int incl = v;
        #pragma unroll
        for (int o = 1; o < 64; o <<= 1) { int u = __shfl_up(incl, o); if (lane >= o) incl += u; }
        if (lane == 63) ws[wid] = incl;
        __syncthreads();
        int wb = 0;
        #pragma unroll
        for (int w = 0; w < 3; ++w) if (w < wid) wb += ws[w];
        sbase[t] = incl - v + wb;
        lh[t] = 0;
    }
    __syncthreads();
    const int bstart = sbase[blockIdx.x];
    const int cnt = gbc[layer * 256 + blockIdx.x];

    for (int i = t; i < cnt; i += 256)
        atomicAdd(&lh[(tp[i] >> 16) & 255], 1);
    __syncthreads();
    {   // exclusive scan lh -> per-node offsets
        int v = lh[t];
        int incl = v;
        #pragma unroll
        for (int o = 1; o < 64; o <<= 1) { int u = __shfl_up(incl, o); if (lane >= o) incl += u; }
        if (lane == 63) ws[wid] = incl;
        __syncthreads();
        int wb = 0;
        #pragma unroll
        for (int w = 0; w < 3; ++w) if (w < wid) wb += ws[w];
        int excl = incl - v + wb;
        int node = node0 + t;
        if (node < N) { offs[node] = bstart + excl; deg[node] = v; }
        lc[t] = bstart + excl;
    }
    __syncthreads();
    for (int i = t; i < cnt; i += 256) {
        uint w = tp[i];
        int p = atomicAdd(&lc[(w >> 16) & 255], 1);
        srcs[p] = (ushort)(w & 0xffff);
    }
}

// ---------------------------------------------------------------------------
// gather-mean over bf16 rows: one wave per node, 16 lanes/edge; uniform
// masked loop keeps 16 row-loads in flight for ANY degree.
// ---------------------------------------------------------------------------
__global__ void gather_mean_b(const ushort* __restrict__ xb, const ushort* __restrict__ srcs,
                              const int* __restrict__ offs, const int* __restrict__ deg,
                              ushort* __restrict__ meanb, int N) {
    int node = blockIdx.x * (blockDim.x >> 6) + (threadIdx.x >> 6);
    if (node >= N) return;
    int lane = threadIdx.x & 63;
    int g = lane >> 4;                // 0..3: edge slot group
    int c = (lane & 15) * 8;          // col base (8 bf16 = 16B per lane)
    int beg = offs[node], dc = deg[node];
    int end = beg + dc;
    float a[8] = {0.f, 0.f, 0.f, 0.f, 0.f, 0.f, 0.f, 0.f};
    for (int base = beg + g; base < end; base += 16) {
        int i0 = base, i1 = base + 4, i2 = base + 8, i3 = base + 12;
        int s0 = srcs[i0 < end ? i0 : beg];
        int s1 = srcs[i1 < end ? i1 : beg];
        int s2 = srcs[i2 < end ? i2 : beg];
        int s3 = srcs[i3 < end ? i3 : beg];
        float w0 = i0 < end ? 1.f : 0.f;
        float w1 = i1 < end ? 1.f : 0.f;
        float w2 = i2 < end ? 1.f : 0.f;
        float w3 = i3 < end ? 1.f : 0.f;
        bf8 v0 = *(const bf8*)(xb + (long)s0 * D + c);
        bf8 v1 = *(const bf8*)(xb + (long)s1 * D + c);
        bf8 v2 = *(const bf8*)(xb + (long)s2 * D + c);
        bf8 v3 = *(const bf8*)(xb + (long)s3 * D + c);
        #pragma unroll
        for (int q = 0; q < 8; ++q) {
            a[q] = fmaf(w0, b2f((ushort)v0[q]), a[q]);
            a[q] = fmaf(w1, b2f((ushort)v1[q]), a[q]);
            a[q] = fmaf(w2, b2f((ushort)v2[q]), a[q]);
            a[q] = fmaf(w3, b2f((ushort)v3[q]), a[q]);
        }
    }
    #pragma unroll
    for (int q = 0; q < 8; ++q) {
        a[q] += __shfl_xor(a[q], 16);
        a[q] += __shfl_xor(a[q], 32);
    }
    if (g == 0) {
        float inv = dc > 0 ? 1.0f / (float)dc : 0.0f;
        bf8 o;
        #pragma unroll
        for (int q = 0; q < 8; ++q) o[q] = (short)f2b(a[q] * inv);
        *(bf8*)(meanb + (long)node * D + c) = o;
    }
}

// ---------------------------------------------------------------------------
// MFMA dual GEMM: out[r] = act( mean[r] @ Wl + bias + x[r] @ Wr )
// W^T pre-swizzled in global; staged LINEARLY into LDS via global_load_lds.
// 4 waves/block, 32 rows/wave, 128 rows/block. Interior blocks (r0+128<=N)
// take a bounds-check-free fast path. Safe in-place (outb == xb).
// ---------------------------------------------------------------------------
template <int ACT>
__global__ __launch_bounds__(256, 2)
void gemm_mfma(const ushort* __restrict__ meanb, const ushort* __restrict__ xb,
               const ushort* __restrict__ WTsw,   // 64KB: [Wl 32KB][Wr 32KB]
               const float* __restrict__ bias, float* __restrict__ outf,
               ushort* __restrict__ outb, int N) {
    __shared__ ushort sW[2 * D * D];   // 64 KB, swizzled (copied linearly)
    const int t = threadIdx.x;
    const int lane = t & 63;
    const int wid  = t >> 6;           // 0..3

    {
        const char* src = (const char*)WTsw;
        char* dst = (char*)sW;
        #pragma unroll
        for (int i = 0; i < 16; ++i) {
            int off = i * 4096 + t * 16;
            __builtin_amdgcn_global_load_lds(
                (const __attribute__((address_space(1))) unsigned int*)(src + off),
                (__attribute__((address_space(3))) unsigned int*)(dst + off),
                16, 0, 0);
        }
    }

    const int r0   = blockIdx.x * 128 + wid * 32;
    const int arow = r0 + (lane & 15);
    const int kg   = lane >> 4;
    const bool full = (r0 + 32 <= N);
    bf8 z = {};
    bf8 am[8], ax[8];                  // [0..3]: rows arow, [4..7]: rows arow+16
    if (full) {
        #pragma unroll
        for (int m = 0; m < 4; ++m) {
            const long a0 = (long)arow * D + kg * 8 + m * 32;
            am[m]   = *(const bf8*)(meanb + a0);
            ax[m]   = *(const bf8*)(xb + a0);
            am[m+4] = *(const bf8*)(meanb + a0 + 16 * D);
            ax[m+4] = *(const bf8*)(xb + a0 + 16 * D);
        }
    } else {
        #pragma unroll
        for (int m = 0; m < 4; ++m) {
            const long a0 = (long)arow * D + kg * 8 + m * 32;
            if (arow < N)      { am[m]   = *(const bf8*)(meanb + a0);
                                 ax[m]   = *(const bf8*)(xb + a0); }
            else               { am[m]   = z; ax[m]   = z; }
            if (arow + 16 < N) { am[m+4] = *(const bf8*)(meanb + a0 + 16 * D);
                                 ax[m+4] = *(const bf8*)(xb + a0 + 16 * D); }
            else               { am[m+4] = z; ax[m+4] = z; }
        }
    }

    const int sxor = (lane & 7) << 4;
    int p[4];
    #pragma unroll
    for (int m = 0; m < 4; ++m)
        p[m] = (lane & 15) * 256 + ((kg * 16 + m * 64) ^ sxor);

    __syncthreads();   // drains global_load_lds too

    f4 acc0[8], acc1[8];
    #pragma unroll
    for (int n = 0; n < 8; ++n) { acc0[n] = (f4){0.f,0.f,0.f,0.f}; acc1[n] = (f4){0.f,0.f,0.f,0.f}; }

    #pragma unroll
    for (int m = 0; m < 4; ++m) {
        #pragma unroll
        for (int n = 0; n < 8; ++n) {
            bf8 bl = *(const bf8*)((const char*)sW + n * 4096 + p[m]);
            acc0[n] = __builtin_amdgcn_mfma_f32_16x16x32_bf16(am[m],     bl, acc0[n], 0, 0, 0);
            acc1[n] = __builtin_amdgcn_mfma_f32_16x16x32_bf16(am[m + 4], bl, acc1[n], 0, 0, 0);
        }
    }
    #pragma unroll
    for (int m = 0; m < 4; ++m) {
        #pragma unroll
        for (int n = 0; n < 8; ++n) {
            bf8 br = *(const bf8*)((const char*)sW + 32768 + n * 4096 + p[m]);
            acc0[n] = __builtin_amdgcn_mfma_f32_16x16x32_bf16(ax[m],     br, acc0[n], 0, 0, 0);
            acc1[n] = __builtin_amdgcn_mfma_f32_16x16x32_bf16(ax[m + 4], br, acc1[n], 0, 0, 0);
        }
    }

    // epilogue: D[row = kg*4 + r (+16)][col = n*16 + (lane&15)]
    const int col0  = lane & 15;
    const int orow0 = r0 + kg * 4;
    #pragma unroll
    for (int n = 0; n < 8; ++n) {
        const int col = n * 16 + col0;
        const float b = bias[col];
        #pragma unroll
        for (int r = 0; r < 4; ++r) {
            #pragma unroll
            for (int h = 0; h < 2; ++h) {
                const int row = orow0 + r + h * 16;
                if (!full && row >= N) continue;
                float v = (h ? acc1[n][r] : acc0[n][r]) + b;
                if (ACT) {
                    v = 0.5f * v * (1.0f + erff(v * 0.70710678118654752f));
                    outb[(long)row * D + col] = f2b(v);
                } else {
                    outf[(long)row * D + col] = v;
                }
            }
        }
    }
}

// ---------------------------------------------------------------------------
extern "C" void kernel_launch(void* const* d_in, const int* in_sizes, int n_in,
                              void* d_out, int out_size, void* d_ws, size_t ws_size,
                              hipStream_t stream) {
    const float* embs = (const float*)d_in[0];
    const int*   ei0  = (const int*)d_in[1];
    const int*   ei1  = (const int*)d_in[2];
    const float* Wl0  = (const float*)d_in[3];
    const float* bl0  = (const float*)d_in[4];
    const float* Wr0  = (const float*)d_in[5];
    const float* Wl1  = (const float*)d_in[6];
    const float* bl1  = (const float*)d_in[7];
    const float* Wr1  = (const float*)d_in[8];

    const int N = in_sizes[0] / D;
    const int E = in_sizes[1] / 2;
    float* out = (float*)d_out;

    const int nbkt = (N + 255) >> BKT_SHIFT;
    const int ncnk = (E + CHUNK - 1) / CHUNK;

    // ws layout
    char* w = (char*)d_ws;
    ushort* xb    = (ushort*)w;  w += (size_t)N * D * 2;      // embs bf16; layer-0 out in-place
    ushort* meanb = (ushort*)w;  w += (size_t)N * D * 2;
    ushort* WT    = (ushort*)w;  w += (size_t)4 * D * D * 2;  // pre-swizzled [Wl0|Wr0|Wl1|Wr1]
    int* gbc      = (int*)w;     w += 512 * 4;                // [2][256] bucket counts
    int* offs0    = (int*)w;     w += (size_t)N * 4;
    int* offs1    = (int*)w;     w += (size_t)N * 4;
    int* deg0     = (int*)w;     w += (size_t)N * 4;
    int* deg1     = (int*)w;     w += (size_t)N * 4;
    uint* tmpf    = (uint*)w;    w += (size_t)2 * 256 * CAP * 4;
    ushort* srcs0 = (ushort*)w;  w += (size_t)256 * CAP * 2;
    ushort* srcs1 = (ushort*)w;

    const int ab = (N + 3) / 4;
    const int gb = (N + 127) / 128;

    zero_gbc<<<1, 512, 0, stream>>>(gbc);
    prep_scatter<<<dim3(ncnk, 3), 256, 0, stream>>>(ei0, ei1, E, gbc, tmpf,
                                                    embs, xb, (long)N * D / 4,
                                                    Wl0, Wr0, Wl1, Wr1, WT);
    exact_place<<<dim3(nbkt, 2), 256, 0, stream>>>(tmpf, gbc, offs0, offs1,
                                                   deg0, deg1, srcs0, srcs1, N);

    // ---- layer 0 ----
    gather_mean_b<<<ab, 256, 0, stream>>>(xb, srcs0, offs0, deg0, meanb, N);
    gemm_mfma<1><<<gb, 256, 0, stream>>>(meanb, xb, WT, bl0, nullptr, xb, N);

    // ---- layer 1 ----
    gather_mean_b<<<ab, 256, 0, stream>>>(xb, srcs1, offs1, deg1, meanb, N);
    gemm_mfma<0><<<gb, 256, 0, stream>>>(meanb, xb, WT + 2 * D * D, bl1, out, nullptr, N);
}